// Round 10
// baseline (153.502 us; speedup 1.0000x reference)
//
#include <hip/hip_runtime.h>
#include <math.h>

// Live dataflow (softmax over singleton axis == 1.0):
//   x (64,8,2048) -> conv1 -> relu/pool -> conv2(fp16 MFMA) -> relu/pool -> mean -> g
//   -> glob = LN(relu(g@w_glob+b_glob)) -> v -> ao = v@out_w.T+out_b -> mlp -> out (64,10)
//
// Round 10: round-8 conv_fused (best: 123.5us) + inline tail via last-16-blocks pattern
// (device-scope gacc atomics + counter; removes tail dispatch + partials round-trip).
// conv2 numerics: single-product fp16 MFMA 32x32x16 (validated r6/r8: absmax 1.2e-4).

typedef __attribute__((ext_vector_type(4))) _Float16 f16x4;
typedef __attribute__((ext_vector_type(8)))  _Float16 f16x8;
typedef __attribute__((ext_vector_type(16))) float    f32x16;

#define H1_OFF   0          // 10 rows * 68 cols * 16 ic * 2B = 21760
#define XS_OFF   21760      // 8*144*4 = 4608
#define GS_OFF   26368      // gacc_s: 32 floats = 128 B
#define LDS_BYTES 26496

template <int CTRL>
__device__ __forceinline__ float dppf(float v) {
    return __uint_as_float(__builtin_amdgcn_update_dpp(
        0u, __float_as_uint(v), CTRL, 0xF, 0xF, true));
}
#define DPP_XOR1 0xB1       // quad_perm [1,0,3,2]
#define DPP_XOR2 0x4E       // quad_perm [2,3,0,1]
#define DPP_ROR4 0x124      // row_ror:4
#define DPP_ROR8 0x128      // row_ror:8

// Build conv2-weight fp16 MFMA A-fragments once: fragg[15][64][8]
__global__ void prep_frags(const float* __restrict__ w2, _Float16* __restrict__ fragg) {
    const int t    = blockIdx.x;       // 0..14 (tap)
    const int lane = threadIdx.x;      // 0..63
    const int kh   = t / 5, kw = t - kh * 5;
    const int oc   = lane & 31;
    const int ic0  = (lane >> 5) * 8;
    f16x8 hv;
    #pragma unroll
    for (int j = 0; j < 8; ++j)
        hv[j] = (_Float16)w2[((oc * 16 + ic0 + j) * 3 + kh) * 5 + kw];
    *(f16x8*)&fragg[(t * 64 + lane) * 8] = hv;
}

__global__ __launch_bounds__(256, 4) void conv_fused(
    const float* __restrict__ x,
    const float* __restrict__ w1, const float* __restrict__ b1,
    const float* __restrict__ b2,
    const _Float16* __restrict__ fragg,
    float* __restrict__ gacc,          // [64 b][32 oc], zeroed by memsetAsync
    int* __restrict__ cnt,             // zeroed by memsetAsync
    const float* __restrict__ w_glob, const float* __restrict__ b_glob,
    const float* __restrict__ g_glob, const float* __restrict__ be_glob,
    const float* __restrict__ in_proj_w, const float* __restrict__ in_proj_b,
    const float* __restrict__ out_w, const float* __restrict__ out_b,
    const float* __restrict__ mlp_w1, const float* __restrict__ mlp_b1,
    const float* __restrict__ mlp_w2, const float* __restrict__ mlp_b2,
    float* __restrict__ out)
{
    const int wt    = blockIdx.x;      // 0..15
    const int b     = blockIdx.y;      // 0..63
    const int linid = b * 16 + wt;     // tail blocks: linid < 16
    const int tid   = threadIdx.x;     // 0..255
    const int w0    = wt * 64;

    __shared__ __align__(16) unsigned int ldsu[LDS_BYTES / 4];
    _Float16* h1    = (_Float16*)((char*)ldsu + H1_OFF);
    float*    xs    = (float*)((char*)ldsu + XS_OFF);
    float*    gaccs = (float*)((char*)ldsu + GS_OFF);

    // ---- per-thread conv1 weights: ic quad q = tid&3 ----
    const int q = tid & 3;
    float wreg[60];
    float bias1[4];
    #pragma unroll
    for (int j = 0; j < 4; ++j) {
        #pragma unroll
        for (int k = 0; k < 15; ++k) wreg[j * 15 + k] = w1[(q * 4 + j) * 15 + k];
        bias1[j] = b1[q * 4 + j];
    }

    // ---- phase 0: stage x tile, zero pad rows, zero gacc_s ----
    const int t0 = 2 * w0 - 6;
    for (int i = tid; i < 8 * 144; i += 256) {
        int r = i / 144, tl = i - r * 144;
        int t = t0 + tl;
        float v = 0.f;
        if (tl < 140 && t >= 0 && t < 2048) v = x[(b * 8 + r) * 2048 + t];
        xs[i] = v;
    }
    {
        unsigned int* hh = (unsigned int*)h1;
        for (int i = tid; i < 544; i += 256) {
            hh[i] = 0u; hh[9 * 544 + i] = 0u;
        }
    }
    if (tid < 32) gaccs[tid] = 0.f;
    __syncthreads();

    // ---- phase 1: conv1 + bias + relu + maxpool -> h1 (fp16) ----
    #pragma unroll
    for (int pass = 0; pass < 3; ++pass) {
        if (pass == 2 && tid >= 32) break;
        const int idx = (tid >> 2) + pass * 64;
        const int r   = idx / 17;
        const int c4  = idx - r * 17;
        const int cb  = c4 * 8;
        float xv[3][12];
        #pragma unroll
        for (int pq = 0; pq < 3; ++pq) {
            int rr = r + pq - 1;
            if (rr >= 0 && rr < 8) {
                const float4* p = (const float4*)&xs[rr * 144 + cb];
                float4 a0 = p[0], a1 = p[1], a2 = p[2];
                xv[pq][0]=a0.x; xv[pq][1]=a0.y; xv[pq][2]=a0.z; xv[pq][3]=a0.w;
                xv[pq][4]=a1.x; xv[pq][5]=a1.y; xv[pq][6]=a1.z; xv[pq][7]=a1.w;
                xv[pq][8]=a2.x; xv[pq][9]=a2.y; xv[pq][10]=a2.z; xv[pq][11]=a2.w;
            } else {
                #pragma unroll
                for (int z = 0; z < 12; ++z) xv[pq][z] = 0.f;
            }
        }
        #pragma unroll
        for (int cc = 0; cc < 4; ++cc) {
            const int wc = w0 - 2 + 4 * c4 + cc;
            f16x4 hv;
            #pragma unroll
            for (int j = 0; j < 4; ++j) {
                float c0 = bias1[j], c1 = bias1[j];
                #pragma unroll
                for (int kh = 0; kh < 3; ++kh)
                    #pragma unroll
                    for (int kw = 0; kw < 5; ++kw) {
                        float wgt = wreg[j * 15 + kh * 5 + kw];
                        c0 = fmaf(xv[kh][2 * cc + kw],     wgt, c0);
                        c1 = fmaf(xv[kh][2 * cc + kw + 1], wgt, c1);
                    }
                float v = fmaxf(fmaxf(c0, c1), 0.f);
                if (wc < 0 || wc >= 1024) v = 0.f;
                hv[j] = (_Float16)v;
            }
            *(f16x4*)&h1[((r + 1) * 68 + 4 * c4 + cc) * 16 + q * 4] = hv;
        }
    }
    __syncthreads();

    // ---- phase 2: conv2 via fp16 MFMA ----
    const int lane  = tid & 63;
    const int wave  = tid >> 6;
    const int laneN = lane & 31;
    const int icoff = (lane >> 5) * 8;
    const int half  = lane >> 5;

    f32x16 acc[4];
    #pragma unroll
    for (int nt = 0; nt < 4; ++nt)
        #pragma unroll
        for (int r = 0; r < 16; ++r) acc[nt][r] = 0.f;

    const f16x8* Ag = (const f16x8*)fragg;
    f16x8 a_cur = Ag[lane];
    for (int t = 0; t < 15; ++t) {
        f16x8 a_nxt = (t < 14) ? Ag[(t + 1) * 64 + lane] : a_cur;
        int kh = t / 5, kw = t - kh * 5;
        #pragma unroll
        for (int nt = 0; nt < 4; ++nt) {
            int hrow = 2 * wave + (nt >> 1);
            int wn0  = (nt & 1) * 32;
            int idx  = ((hrow + kh) * 68 + wn0 + laneN + kw) * 16 + icoff;
            f16x8 bv = *(const f16x8*)&h1[idx];
            acc[nt] = __builtin_amdgcn_mfma_f32_32x32x16_f16(a_cur, bv, acc[nt], 0, 0, 0);
        }
        a_cur = a_nxt;
    }

    // ---- epilogue: +bias, relu(pool) via DPP, 16-lane DPP sum, LDS-atomic reduce ----
    float b2v[16], sums[16];
    #pragma unroll
    for (int r = 0; r < 16; ++r) {
        b2v[r]  = b2[(r & 3) + 8 * (r >> 2) + 4 * half];
        sums[r] = 0.f;
    }
    #pragma unroll
    for (int nt = 0; nt < 4; ++nt)
        #pragma unroll
        for (int r = 0; r < 16; ++r) {
            float d = acc[nt][r] + b2v[r];
            float o = fmaxf(fmaxf(d, dppf<DPP_XOR1>(d)), 0.f);   // pool pair + relu
            sums[r] += o;                                         // each pair counted twice
        }
    #pragma unroll
    for (int r = 0; r < 16; ++r) {
        float s = sums[r];
        s += dppf<DPP_XOR1>(s);
        s += dppf<DPP_XOR2>(s);
        s += dppf<DPP_ROR4>(s);
        s += dppf<DPP_ROR8>(s);
        sums[r] = s;
    }
    if ((lane & 15) == 0) {
        #pragma unroll
        for (int r = 0; r < 16; ++r) {
            int oc = (r & 3) + 8 * (r >> 2) + 4 * half;
            atomicAdd(&gaccs[oc], sums[r]);
        }
    }
    __syncthreads();
    if (tid < 32) atomicAdd(&gacc[b * 32 + tid], 0.5f * gaccs[tid]);
    __syncthreads();                    // drain all waves' atomics (vmcnt0 at barrier)
    if (tid == 0) { __threadfence(); atomicAdd(cnt, 1); }

    // ---- inline tail: first 16 blocks (by id) wait for all 1024, then 1 b per wave ----
    if (linid < 16) {
        if (tid == 0) { while (atomicAdd(cnt, 0) < 1024) { } }
        __syncthreads();
        __threadfence();
        const int bt = linid * 4 + wave;          // 0..63
        float* tl     = (float*)ldsu + wave * 256;  // per-wave 256-float slice (reuses h1)
        float* gs     = tl;
        float* glob_s = tl + 32;
        float* vs     = tl + 96;
        float* aos    = tl + 160;
        float* hms    = tl + 224;

        if (lane < 32) {
            float gv = atomicAdd(&gacc[bt * 32 + lane], 0.0f);   // coherent read
            gs[lane] = gv * (1.f / 4096.f);
        }
        __syncthreads();

        float a2 = b_glob[lane];
        #pragma unroll
        for (int i = 0; i < 32; ++i) a2 = fmaf(gs[i], w_glob[i * 64 + lane], a2);
        a2 = fmaxf(a2, 0.f);

        float m = a2;
        #pragma unroll
        for (int k = 32; k >= 1; k >>= 1) m += __shfl_xor(m, k);
        m *= (1.f / 64.f);
        float d = a2 - m;
        float vv = d * d;
        #pragma unroll
        for (int k = 32; k >= 1; k >>= 1) vv += __shfl_xor(vv, k);
        vv *= (1.f / 64.f);
        float gl = d * (1.f / sqrtf(vv + 1e-5f)) * g_glob[lane] + be_glob[lane];
        glob_s[lane] = gl;
        __syncthreads();

        float vval = in_proj_b[128 + lane];
        #pragma unroll
        for (int j = 0; j < 64; ++j)
            vval = fmaf(glob_s[j], in_proj_w[(128 + lane) * 64 + j], vval);
        vs[lane] = vval;
        __syncthreads();

        float ao = out_b[lane];
        #pragma unroll
        for (int j = 0; j < 64; ++j) ao = fmaf(vs[j], out_w[lane * 64 + j], ao);
        aos[lane] = ao;
        __syncthreads();

        if (lane < 32) {
            float hm = mlp_b1[lane];
            #pragma unroll
            for (int j = 0; j < 64; ++j) hm = fmaf(aos[j], mlp_w1[j * 32 + lane], hm);
            hms[lane] = fmaxf(hm, 0.f);
        }
        __syncthreads();

        if (lane < 10) {
            float o = mlp_b2[lane];
            #pragma unroll
            for (int i = 0; i < 32; ++i) o = fmaf(hms[i], mlp_w2[i * 10 + lane], o);
            out[bt * 10 + lane] = o;
        }
    }
}

extern "C" void kernel_launch(void* const* d_in, const int* in_sizes, int n_in,
                              void* d_out, int out_size, void* d_ws, size_t ws_size,
                              hipStream_t stream) {
    const float* x        = (const float*)d_in[0];
    const float* conv1_w  = (const float*)d_in[6];
    const float* conv1_b  = (const float*)d_in[7];
    const float* conv2_w  = (const float*)d_in[8];
    const float* conv2_b  = (const float*)d_in[9];
    const float* w_glob   = (const float*)d_in[10];
    const float* b_glob   = (const float*)d_in[11];
    const float* g_glob   = (const float*)d_in[12];
    const float* be_glob  = (const float*)d_in[13];
    const float* in_proj_w = (const float*)d_in[14];
    const float* in_proj_b = (const float*)d_in[15];
    const float* out_w    = (const float*)d_in[16];
    const float* out_b    = (const float*)d_in[17];
    const float* mlp_w1   = (const float*)d_in[18];
    const float* mlp_b1   = (const float*)d_in[19];
    const float* mlp_w2   = (const float*)d_in[20];
    const float* mlp_b2   = (const float*)d_in[21];

    _Float16* fragg = (_Float16*)d_ws;                     // 15360 B
    float* gacc     = (float*)((char*)d_ws + 15360);       // 64*32*4 = 8192 B
    int*   cnt      = (int*)((char*)d_ws + 15360 + 8192);  // 4 B

    hipMemsetAsync((char*)d_ws + 15360, 0, 8192 + 4, stream);

    prep_frags<<<15, 64, 0, stream>>>(conv2_w, fragg);

    dim3 grid(16, 64);
    conv_fused<<<grid, 256, 0, stream>>>(x, conv1_w, conv1_b, conv2_b, fragg,
                                         gacc, cnt,
                                         w_glob, b_glob, g_glob, be_glob,
                                         in_proj_w, in_proj_b, out_w, out_b,
                                         mlp_w1, mlp_b1, mlp_w2, mlp_b2,
                                         (float*)d_out);
}

// Round 11
// 123.674 us; speedup vs baseline: 1.2412x; 1.2412x over previous
//
#include <hip/hip_runtime.h>
#include <math.h>

// Live dataflow (softmax over singleton axis == 1.0):
//   x (64,8,2048) -> conv1(16,1,3,5 pad(1,2)) +bias,relu -> maxpool W/2 -> (64,16,8,1024)
//   -> conv2(32,16,3,5 pad(1,2)) +bias,relu -> maxpool W/2 -> mean(H,W) -> g (64,32)
//   -> glob = LN(relu(g@w_glob+b_glob)) -> v = glob@wv.T+bv -> ao = v@out_w.T+out_b
//   -> hmid = relu(ao@mlp_w1+mlp_b1) -> out = hmid@mlp_w2+mlp_b2  (64,10)
//
// conv2: single-product fp16 MFMA 32x32x16 (validated r6/r8: absmax 1.2e-4 << 7.5e-4).
// Round 11: exact revert to round-8 structure (best measured: 123.5 us).
// r9 (kernel split, h1 via global) and r10 (fused tail + device atomics) both regressed;
// the 3-dispatch shape with LDS-resident h1 is the proven local optimum.

typedef __attribute__((ext_vector_type(4))) _Float16 f16x4;
typedef __attribute__((ext_vector_type(8)))  _Float16 f16x8;
typedef __attribute__((ext_vector_type(16))) float    f32x16;

#define WT 64
#define NT 16
#define H1_OFF   0          // 10 rows * 68 cols * 16 ic * 2B = 21760
#define XS_OFF   21760      // 8*144*4 = 4608
#define LDS_BYTES 26368

template <int CTRL>
__device__ __forceinline__ float dppf(float v) {
    return __uint_as_float(__builtin_amdgcn_update_dpp(
        0u, __float_as_uint(v), CTRL, 0xF, 0xF, true));
}
#define DPP_XOR1 0xB1       // quad_perm [1,0,3,2]
#define DPP_XOR2 0x4E       // quad_perm [2,3,0,1]
#define DPP_ROR4 0x124      // row_ror:4
#define DPP_ROR8 0x128      // row_ror:8

// Build conv2-weight fp16 MFMA A-fragments once: fragg[15][64][8]
__global__ void prep_frags(const float* __restrict__ w2, _Float16* __restrict__ fragg) {
    const int t    = blockIdx.x;       // 0..14 (tap)
    const int lane = threadIdx.x;      // 0..63
    const int kh   = t / 5, kw = t - kh * 5;
    const int oc   = lane & 31;
    const int ic0  = (lane >> 5) * 8;
    f16x8 hv;
    #pragma unroll
    for (int j = 0; j < 8; ++j)
        hv[j] = (_Float16)w2[((oc * 16 + ic0 + j) * 3 + kh) * 5 + kw];
    *(f16x8*)&fragg[(t * 64 + lane) * 8] = hv;
}

__global__ __launch_bounds__(256, 4) void conv_fused(
    const float* __restrict__ x,
    const float* __restrict__ w1, const float* __restrict__ b1,
    const float* __restrict__ b2,
    const _Float16* __restrict__ fragg,
    float* __restrict__ part)    // [64 b][32 oc][16 wt][4 wave][2 nhalf]
{
    const int wt  = blockIdx.x;      // 0..15
    const int b   = blockIdx.y;      // 0..63
    const int tid = threadIdx.x;     // 0..255
    const int w0  = wt * WT;

    __shared__ __align__(16) unsigned int ldsu[LDS_BYTES / 4];
    _Float16* h1 = (_Float16*)((char*)ldsu + H1_OFF);  // [(rr*68+c)*16+ic], rr=0..9 (0,9 zero)
    float*    xs = (float*)((char*)ldsu + XS_OFF);     // [8][144]

    // ---- per-thread conv1 weights: ic quad q = tid&3 (thread-constant) ----
    const int q = tid & 3;
    float wreg[60];
    float bias1[4];
    #pragma unroll
    for (int j = 0; j < 4; ++j) {
        #pragma unroll
        for (int k = 0; k < 15; ++k) wreg[j * 15 + k] = w1[(q * 4 + j) * 15 + k];
        bias1[j] = b1[q * 4 + j];
    }

    // ---- phase 0: stage x tile (cols t0..t0+139), zero pad rows rr=0,9 ----
    const int t0 = 2 * w0 - 6;
    for (int i = tid; i < 8 * 144; i += 256) {
        int r = i / 144, tl = i - r * 144;
        int t = t0 + tl;
        float v = 0.f;
        if (tl < 140 && t >= 0 && t < 2048) v = x[(b * 8 + r) * 2048 + t];
        xs[i] = v;
    }
    {
        unsigned int* hh = (unsigned int*)h1;
        for (int i = tid; i < 544; i += 256) {       // each padded row = 544 dwords
            hh[i] = 0u; hh[4896 + i] = 0u;
        }
    }
    __syncthreads();

    // ---- phase 1: conv1 + bias + relu + maxpool -> h1 (fp16) ----
    // item id e in [0,544): idx = e>>2 in [0,136) -> (r = idx/17, c4 = idx%17); quad q = e&3.
    // thread handles items {tid, tid+256} and (tid<32) item tid+512 -> q == tid&3 for all.
    #pragma unroll
    for (int pass = 0; pass < 3; ++pass) {
        if (pass == 2 && tid >= 32) break;
        const int idx = (tid >> 2) + pass * 64;      // 0..135
        const int r   = idx / 17;
        const int c4  = idx - r * 17;
        const int cb  = c4 * 8;
        float xv[3][12];
        #pragma unroll
        for (int pq = 0; pq < 3; ++pq) {
            int rr = r + pq - 1;
            if (rr >= 0 && rr < 8) {
                const float4* p = (const float4*)&xs[rr * 144 + cb];
                float4 a0 = p[0], a1 = p[1], a2 = p[2];
                xv[pq][0]=a0.x; xv[pq][1]=a0.y; xv[pq][2]=a0.z; xv[pq][3]=a0.w;
                xv[pq][4]=a1.x; xv[pq][5]=a1.y; xv[pq][6]=a1.z; xv[pq][7]=a1.w;
                xv[pq][8]=a2.x; xv[pq][9]=a2.y; xv[pq][10]=a2.z; xv[pq][11]=a2.w;
            } else {
                #pragma unroll
                for (int z = 0; z < 12; ++z) xv[pq][z] = 0.f;
            }
        }
        #pragma unroll
        for (int cc = 0; cc < 4; ++cc) {
            const int wc = w0 - 2 + 4 * c4 + cc;
            f16x4 hv;
            #pragma unroll
            for (int j = 0; j < 4; ++j) {
                float c0 = bias1[j], c1 = bias1[j];
                #pragma unroll
                for (int kh = 0; kh < 3; ++kh)
                    #pragma unroll
                    for (int kw = 0; kw < 5; ++kw) {
                        float wgt = wreg[j * 15 + kh * 5 + kw];
                        c0 = fmaf(xv[kh][2 * cc + kw],     wgt, c0);
                        c1 = fmaf(xv[kh][2 * cc + kw + 1], wgt, c1);
                    }
                float v = fmaxf(fmaxf(c0, c1), 0.f);
                if (wc < 0 || wc >= 1024) v = 0.f;
                hv[j] = (_Float16)v;
            }
            *(f16x4*)&h1[((r + 1) * 68 + 4 * c4 + cc) * 16 + q * 4] = hv;  // 8B store
        }
    }
    __syncthreads();

    // ---- phase 2: conv2 via fp16 MFMA. wave handles h rows {2w,2w+1} x wn0 {0,32} ----
    const int lane  = tid & 63;
    const int wave  = tid >> 6;
    const int laneN = lane & 31;
    const int icoff = (lane >> 5) * 8;
    const int half  = lane >> 5;

    f32x16 acc[4];
    #pragma unroll
    for (int nt = 0; nt < 4; ++nt)
        #pragma unroll
        for (int r = 0; r < 16; ++r) acc[nt][r] = 0.f;

    const f16x8* Ag = (const f16x8*)fragg;
    f16x8 a_cur = Ag[lane];                          // tap 0 (L1/L2-resident)
    for (int t = 0; t < 15; ++t) {
        f16x8 a_nxt = (t < 14) ? Ag[(t + 1) * 64 + lane] : a_cur;  // 1-deep prefetch
        int kh = t / 5, kw = t - kh * 5;             // wave-uniform
        #pragma unroll
        for (int nt = 0; nt < 4; ++nt) {
            int hrow = 2 * wave + (nt >> 1);
            int wn0  = (nt & 1) * 32;
            int idx  = ((hrow + kh) * 68 + wn0 + laneN + kw) * 16 + icoff;
            f16x8 bv = *(const f16x8*)&h1[idx];
            acc[nt] = __builtin_amdgcn_mfma_f32_32x32x16_f16(a_cur, bv, acc[nt], 0, 0, 0);
        }
        a_cur = a_nxt;
    }

    // ---- epilogue (VALU/DPP): +bias, relu(maxpool) via DPP xor1, 16-lane DPP sum ----
    float b2v[16], sums[16];
    #pragma unroll
    for (int r = 0; r < 16; ++r) {
        b2v[r]  = b2[(r & 3) + 8 * (r >> 2) + 4 * half];
        sums[r] = 0.f;
    }
    #pragma unroll
    for (int nt = 0; nt < 4; ++nt)
        #pragma unroll
        for (int r = 0; r < 16; ++r) {
            float d = acc[nt][r] + b2v[r];
            float o = fmaxf(fmaxf(d, dppf<DPP_XOR1>(d)), 0.f);  // pool pair + relu
            sums[r] += o;                                        // counts each pair twice
        }
    #pragma unroll
    for (int r = 0; r < 16; ++r) {
        float s = sums[r];
        s += dppf<DPP_XOR1>(s);
        s += dppf<DPP_XOR2>(s);
        s += dppf<DPP_ROR4>(s);
        s += dppf<DPP_ROR8>(s);      // full sum within each 16-lane group
        sums[r] = s;
    }
    if ((lane & 15) == 0) {          // lanes 0,16,32,48: two n-halves x two K-halves
        const int nh = (lane >> 4) & 1;
        #pragma unroll
        for (int r = 0; r < 16; ++r) {
            int oc = (r & 3) + 8 * (r >> 2) + 4 * half;
            part[((b * 32 + oc) * 16 + wt) * 8 + wave * 2 + nh] = 0.5f * sums[r];
        }
    }
}

__global__ void tail_kernel(
    const float* __restrict__ part,
    const float* __restrict__ w_glob, const float* __restrict__ b_glob,
    const float* __restrict__ g_glob, const float* __restrict__ be_glob,
    const float* __restrict__ in_proj_w, const float* __restrict__ in_proj_b,
    const float* __restrict__ out_w, const float* __restrict__ out_b,
    const float* __restrict__ mlp_w1, const float* __restrict__ mlp_b1,
    const float* __restrict__ mlp_w2, const float* __restrict__ mlp_b2,
    float* __restrict__ out)
{
    const int b = blockIdx.x;        // 0..63
    const int e = threadIdx.x;       // 0..63 (one wave)
    __shared__ float gs[32], glob_s[64], vs[64], aos[64], hms[32];

    if (e < 32) {
        float sm = 0.f;
        #pragma unroll
        for (int t = 0; t < 128; ++t) sm += part[(b * 32 + e) * 128 + t];
        gs[e] = sm * (1.f / 4096.f);  // mean over 8*512
    }
    __syncthreads();

    float acc = b_glob[e];
    #pragma unroll
    for (int i = 0; i < 32; ++i) acc = fmaf(gs[i], w_glob[i * 64 + e], acc);
    acc = fmaxf(acc, 0.f);

    float m = acc;
    #pragma unroll
    for (int k = 32; k >= 1; k >>= 1) m += __shfl_xor(m, k);
    m *= (1.f / 64.f);
    float d = acc - m;
    float vv = d * d;
    #pragma unroll
    for (int k = 32; k >= 1; k >>= 1) vv += __shfl_xor(vv, k);
    vv *= (1.f / 64.f);
    float gl = d * (1.f / sqrtf(vv + 1e-5f)) * g_glob[e] + be_glob[e];
    glob_s[e] = gl;
    __syncthreads();

    float vval = in_proj_b[128 + e];
    #pragma unroll
    for (int j = 0; j < 64; ++j) vval = fmaf(glob_s[j], in_proj_w[(128 + e) * 64 + j], vval);
    vs[e] = vval;
    __syncthreads();

    float ao = out_b[e];
    #pragma unroll
    for (int j = 0; j < 64; ++j) ao = fmaf(vs[j], out_w[e * 64 + j], ao);
    aos[e] = ao;
    __syncthreads();

    if (e < 32) {
        float hm = mlp_b1[e];
        #pragma unroll
        for (int j = 0; j < 64; ++j) hm = fmaf(aos[j], mlp_w1[j * 32 + e], hm);
        hms[e] = fmaxf(hm, 0.f);
    }
    __syncthreads();

    if (e < 10) {
        float o = mlp_b2[e];
        #pragma unroll
        for (int i = 0; i < 32; ++i) o = fmaf(hms[i], mlp_w2[i * 10 + e], o);
        out[b * 10 + e] = o;
    }
}

extern "C" void kernel_launch(void* const* d_in, const int* in_sizes, int n_in,
                              void* d_out, int out_size, void* d_ws, size_t ws_size,
                              hipStream_t stream) {
    const float* x        = (const float*)d_in[0];
    const float* conv1_w  = (const float*)d_in[6];
    const float* conv1_b  = (const float*)d_in[7];
    const float* conv2_w  = (const float*)d_in[8];
    const float* conv2_b  = (const float*)d_in[9];
    const float* w_glob   = (const float*)d_in[10];
    const float* b_glob   = (const float*)d_in[11];
    const float* g_glob   = (const float*)d_in[12];
    const float* be_glob  = (const float*)d_in[13];
    const float* in_proj_w = (const float*)d_in[14];
    const float* in_proj_b = (const float*)d_in[15];
    const float* out_w    = (const float*)d_in[16];
    const float* out_b    = (const float*)d_in[17];
    const float* mlp_w1   = (const float*)d_in[18];
    const float* mlp_b1   = (const float*)d_in[19];
    const float* mlp_w2   = (const float*)d_in[20];
    const float* mlp_b2   = (const float*)d_in[21];

    _Float16* fragg = (_Float16*)d_ws;                            // 15*64*8*2 = 15360 B
    float* partials = (float*)((char*)d_ws + 15360);              // 64*32*16*8 floats = 1 MB

    prep_frags<<<15, 64, 0, stream>>>(conv2_w, fragg);

    dim3 grid(NT, 64);
    conv_fused<<<grid, 256, 0, stream>>>(x, conv1_w, conv1_b, conv2_b, fragg, partials);

    tail_kernel<<<64, 64, 0, stream>>>(partials, w_glob, b_glob, g_glob, be_glob,
                                       in_proj_w, in_proj_b, out_w, out_b,
                                       mlp_w1, mlp_b1, mlp_w2, mlp_b2,
                                       (float*)d_out);
}